// Round 5
// baseline (208.135 us; speedup 1.0000x reference)
//
#include <hip/hip_runtime.h>

// out[b,h,w,d] = sum_c x[b,h,w,c] * w[c,d]   with C=D=3, fp32.
//
// R4 lesson: strided-direct (62us), LDS-staged stride-1 (~60us) — identical.
// Coalescing pattern is NOT the limiter. The poison-fill hits 6.6 TB/s at 9%
// occupancy / 8 VGPRs: BW is driven by outstanding VMEM bytes per wave.
// Our kernels all had only 3 loads in flight before a dependent stall.
//
// This version: grid-stride-free, depth-4 per thread. ALL 12 float4 loads
// issued back-to-back (192B/lane outstanding, 4x previous MLP), then
// compute + 12 nontemporal stores. No LDS, no barriers.
// chunk c = 4 pixels = 3 float4. Thread handles chunks base+k*256, k=0..3.

typedef float f4 __attribute__((ext_vector_type(4)));

#define DEPTH 4
#define BLOCK 256
#define CHUNKS_PER_BLOCK (BLOCK * DEPTH)   // 1024 chunks = 4096 pixels

__global__ __launch_bounds__(BLOCK) void mct_kernel(
    const float* __restrict__ x,
    const float* __restrict__ w,
    float* __restrict__ out,
    long long n_chunks,
    long long n_pixels)
{
    const int tid = threadIdx.x;
    const long long blk_base = (long long)blockIdx.x * CHUNKS_PER_BLOCK;
    const long long base = blk_base + tid;   // chunk index for k=0

    const float w00 = w[0], w01 = w[1], w02 = w[2];
    const float w10 = w[3], w11 = w[4], w12 = w[5];
    const float w20 = w[6], w21 = w[7], w22 = w[8];

    const f4* __restrict__ src = reinterpret_cast<const f4*>(x);
    f4* __restrict__ dst = reinterpret_cast<f4*>(out);

    if (blk_base + CHUNKS_PER_BLOCK <= n_chunks) {
        // Fast path: whole block in range. Hoist all 12 loads.
        f4 v[DEPTH * 3];
#pragma unroll
        for (int k = 0; k < DEPTH; ++k) {
            const long long c = (base + (long long)k * BLOCK) * 3;
            v[k * 3 + 0] = src[c + 0];
            v[k * 3 + 1] = src[c + 1];
            v[k * 3 + 2] = src[c + 2];
        }
#pragma unroll
        for (int k = 0; k < DEPTH; ++k) {
            f4 a = v[k * 3 + 0], b = v[k * 3 + 1], c = v[k * 3 + 2];
            f4 oa, ob, oc;
            oa.x = a.x * w00 + a.y * w10 + a.z * w20;
            oa.y = a.x * w01 + a.y * w11 + a.z * w21;
            oa.z = a.x * w02 + a.y * w12 + a.z * w22;
            oa.w = a.w * w00 + b.x * w10 + b.y * w20;
            ob.x = a.w * w01 + b.x * w11 + b.y * w21;
            ob.y = a.w * w02 + b.x * w12 + b.y * w22;
            ob.z = b.z * w00 + b.w * w10 + c.x * w20;
            ob.w = b.z * w01 + b.w * w11 + c.x * w21;
            oc.x = b.z * w02 + b.w * w12 + c.x * w22;
            oc.y = c.y * w00 + c.z * w10 + c.w * w20;
            oc.z = c.y * w01 + c.z * w11 + c.w * w21;
            oc.w = c.y * w02 + c.z * w12 + c.w * w22;
            const long long cc = (base + (long long)k * BLOCK) * 3;
            __builtin_nontemporal_store(oa, dst + cc + 0);
            __builtin_nontemporal_store(ob, dst + cc + 1);
            __builtin_nontemporal_store(oc, dst + cc + 2);
        }
    } else {
        // Tail block: per-chunk guarded, then pixel tail.
        for (int k = 0; k < DEPTH; ++k) {
            const long long ci = base + (long long)k * BLOCK;
            if (ci < n_chunks) {
                const long long c = ci * 3;
                f4 a = src[c + 0], b = src[c + 1], cv = src[c + 2];
                f4 oa, ob, oc;
                oa.x = a.x * w00 + a.y * w10 + a.z * w20;
                oa.y = a.x * w01 + a.y * w11 + a.z * w21;
                oa.z = a.x * w02 + a.y * w12 + a.z * w22;
                oa.w = a.w * w00 + b.x * w10 + b.y * w20;
                ob.x = a.w * w01 + b.x * w11 + b.y * w21;
                ob.y = a.w * w02 + b.x * w12 + b.y * w22;
                ob.z = b.z * w00 + b.w * w10 + cv.x * w20;
                ob.w = b.z * w01 + b.w * w11 + cv.x * w21;
                oc.x = b.z * w02 + b.w * w12 + cv.x * w22;
                oc.y = cv.y * w00 + cv.z * w10 + cv.w * w20;
                oc.z = cv.y * w01 + cv.z * w11 + cv.w * w21;
                oc.w = cv.y * w02 + cv.z * w12 + cv.w * w22;
                dst[c + 0] = oa;
                dst[c + 1] = ob;
                dst[c + 2] = oc;
            }
        }
        // Pixel tail (n_pixels % 4) — only the last block's first threads.
        const long long tail_start = n_chunks * 4;
        const long long n_tail = n_pixels - tail_start;
        if (tid < n_tail) {
            const long long p = tail_start + tid;
            const float x0 = x[p * 3 + 0];
            const float x1 = x[p * 3 + 1];
            const float x2 = x[p * 3 + 2];
            out[p * 3 + 0] = x0 * w00 + x1 * w10 + x2 * w20;
            out[p * 3 + 1] = x0 * w01 + x1 * w11 + x2 * w21;
            out[p * 3 + 2] = x0 * w02 + x1 * w12 + x2 * w22;
        }
    }
}

extern "C" void kernel_launch(void* const* d_in, const int* in_sizes, int n_in,
                              void* d_out, int out_size, void* d_ws, size_t ws_size,
                              hipStream_t stream) {
    const float* x = (const float*)d_in[0];
    const float* w = (const float*)d_in[1];
    float* out = (float*)d_out;

    const long long n_total  = (long long)in_sizes[0];   // 32*512*512*3
    const long long n_pixels = n_total / 3;
    const long long n_chunks = n_pixels / 4;

    long long grid = (n_chunks + CHUNKS_PER_BLOCK - 1) / CHUNKS_PER_BLOCK; // 2048
    if (grid < 1) grid = 1;

    mct_kernel<<<(int)grid, BLOCK, 0, stream>>>(x, w, out, n_chunks, n_pixels);
}